// Round 13
// baseline (107.027 us; speedup 1.0000x reference)
//
#include <hip/hip_runtime.h>

// ---------------------------------------------------------------------------
// x(2,32,16,16,16), w_init(32,32,27), w_qkv(96,32,27), w_out(32,32), b_out(32).
// out(2,64,4096). heads=4, dk_h=dv_h=8, N=4096, scale=8^-0.5 (folded into the
// q-weights together with log2e; softmax uses exp2).
// 3 kernels: kConv (self-staging weights + x transpose; 27 tap-shifted bf16
// MFMA GEMMs, K=32=ic), kAttn (bf16 MFMA, key-split KSP, 2 n-tiles/wave,
// full-wave K loads + dual Q A-variants, read-before-write P pipeline,
// BRANCHLESS PV B-operand via 16-row VtTp: rows 0-7 = V, row 8 = 1.0 ->
// row-sum l for free, rows 9-15 = 0), kOut (merge + 1x1x1 conv fused).
// ---------------------------------------------------------------------------

typedef short short8 __attribute__((ext_vector_type(8)));
typedef float float4v __attribute__((ext_vector_type(4)));
typedef unsigned short ushort_t;
typedef unsigned int uint_t;

__device__ inline ushort_t f2bf(float x) {   // fp32 -> bf16 RNE (scalar path)
  uint_t u = __builtin_bit_cast(uint_t, x);
  u += 0x7FFFu + ((u >> 16) & 1u);
  return (ushort_t)(u >> 16);
}

__device__ inline uint_t cvtpk(float lo, float hi) {  // packed bf16x2, RNE, 1 inst
  uint_t r;
  asm("v_cvt_pk_bf16_f32 %0, %1, %2" : "=v"(r) : "v"(lo), "v"(hi));
  return r;
}

// MFMA conv, fully self-staging. Block=(b,z,oq), grid 256 (1 block/CU), 4 waves.
// Phase W: stage this block's CONTIGUOUS 54KB weight slice (o-major layout!)
//   into wl[tap(27)][lane(64)][j(8)] bf16: o = oq*16 + (lane&15),
//   ic = (lane>>4)*8 + j. q-tiles (oq 2,3) pre-scaled by QS.
// Phase X (per kz): transpose wrapped z-plane x fp32 (b,ic,s) -> xs[s][ic]
//   bf16 via 34-padded LDS staging (2 halves of 128 rows, float4 loads),
//   then 9 taps of MFMA (afrag from wl, bfrag from xs, both ds_read_b128).
// oq==7 blocks additionally write VtTp's constant rows (8 = ones, 9-15 = 0).
// LDS: 16KB xs + 17.4KB xsf + 27KB wl = 60.4KB (static, under 64KB).
__global__ __launch_bounds__(256, 1) void kConv(const float* __restrict__ x,
                                                const float* __restrict__ w_init,
                                                const float* __restrict__ w_qkv,
                                                float* __restrict__ out,
                                                ushort_t* __restrict__ Qbf,
                                                ushort_t* __restrict__ Kbf,
                                                ushort_t* __restrict__ VtTp) {
  __shared__ ushort_t wl[27 * 512];     // 27 KB
  __shared__ ushort_t xs[256 * 32];     // 16 KB: one z-plane, [s=y*16+x][ic]
  __shared__ float xsf[128 * 34];       // 17 KB: half-plane transpose staging
  int tid = threadIdx.x;
  int w = tid >> 6, lane = tid & 63;
  int quad = lane >> 4, nl = lane & 15;
  int bx = blockIdx.x;              // [0,256) = b*128 + z*8 + oq
  int oq = bx & 7;
  int z = (bx >> 3) & 15;
  int b = bx >> 7;

  // ---- Phase W: weight slice -> wl (contiguous 3456 float4 reads)
  const float* wsrc = (oq < 2) ? (w_init + (size_t)oq * 16 * 864)
                               : (w_qkv + (size_t)(oq - 2) * 16 * 864);  // 864=32*27
  const float QS = 0.35355339059327373f * 1.4426950408889634f;
  float wscale = (oq == 2 || oq == 3) ? QS : 1.0f;
#pragma unroll
  for (int i = 0; i < 14; ++i) {
    int idx4 = i * 256 + tid;          // float4 index [0, 3456)
    if (idx4 < 3456) {
      float4 v = *(const float4*)(wsrc + (size_t)idx4 * 4);
      float vv[4] = {v.x, v.y, v.z, v.w};
#pragma unroll
      for (int k = 0; k < 4; ++k) {
        int e = idx4 * 4 + k;          // = (oo*32 + ic)*27 + tap
        int tap = e % 27;
        int rest = e / 27;
        int ic = rest & 31;
        int oo = rest >> 5;
        wl[tap * 512 + ((ic >> 3) * 16 + oo) * 8 + (ic & 7)] = f2bf(vv[k] * wscale);
      }
    }
  }

  // ---- constant VtTp rows (8 = bf16 1.0, 9..15 = 0), written by oq==7 blocks
  if (oq == 7) {
#pragma unroll
    for (int i = 0; i < 4; ++i) {
      int idx = i * 256 + tid;         // [0,1024): row = idx>>5, sB = idx&31
      int row = idx >> 5;              // h*8 + rr, rr in [0,8)
      int h = row >> 3, rr = row & 7;
      ushort_t val = (rr == 0) ? (ushort_t)0x3F80 : (ushort_t)0;
      short8 v8;
#pragma unroll
      for (int j = 0; j < 8; ++j) v8[j] = (short)val;
      *(short8*)(VtTp + ((size_t)((b * 4 + h) * 16) + 8 + rr) * 4096
                 + z * 256 + (idx & 31) * 8) = v8;
    }
  }

  float4v acc[4];
#pragma unroll
  for (int st = 0; st < 4; ++st) acc[st] = (float4v){0.f, 0.f, 0.f, 0.f};
  int y0 = w * 4;

  for (int kz = 0; kz < 3; ++kz) {
    int zr = (z + kz + 15) & 15;
    // ---- Phase X: stage plane zr -> xs[s][ic] bf16, 2 halves of 128 rows
#pragma unroll
    for (int h = 0; h < 2; ++h) {
      __syncthreads();   // xsf free (prev pack / prev kz's mfma reads done)
#pragma unroll
      for (int i = 0; i < 4; ++i) {
        int q = i * 256 + tid;         // float4 slot [0,1024)
        int ic = q >> 5;
        int sq = q & 31;               // covers s = h*128 + sq*4 .. +3
        float4 v = *(const float4*)(x + ((size_t)(b * 32 + ic) * 16 + zr) * 256
                                      + h * 128 + sq * 4);
        float vv[4] = {v.x, v.y, v.z, v.w};
#pragma unroll
        for (int j = 0; j < 4; ++j) xsf[(sq * 4 + j) * 34 + ic] = vv[j];
      }
      __syncthreads();
#pragma unroll
      for (int r = 0; r < 2; ++r) {
        int slot = r * 256 + tid;      // [0,512) = 128 rows x 4 ic-groups
        int sl = slot >> 2;
        int icg = slot & 3;
        ushort_t tmp[8];
#pragma unroll
        for (int jj = 0; jj < 8; ++jj) tmp[jj] = f2bf(xsf[sl * 34 + icg * 8 + jj]);
        *(short8*)(xs + (h * 128 + sl) * 32 + icg * 8) = *(short8*)tmp;
      }
    }
    __syncthreads();

    // ---- 9 taps of this kz-plane
#pragma unroll
    for (int kyx = 0; kyx < 9; ++kyx) {
      int ky = kyx / 3, kx = kyx % 3;
      int tap = kz * 9 + kyx;
      short8 afrag = *(const short8*)(wl + tap * 512 + lane * 8);
      int xsh = (nl + kx + 15) & 15;
#pragma unroll
      for (int st = 0; st < 4; ++st) {
        int yy = (y0 + st + ky + 15) & 15;
        short8 bfrag = *(const short8*)(xs + (yy * 16 + xsh) * 32 + quad * 8);
        acc[st] = __builtin_amdgcn_mfma_f32_16x16x32_bf16(afrag, bfrag, acc[st], 0, 0, 0);
      }
    }
  }

  // Epilogue. C layout: col = nl (spatial x), row = quad*4 + r (o in tile).
#pragma unroll
  for (int st = 0; st < 4; ++st) {
    int y = y0 + st;
    int s = z * 256 + y * 16 + nl;
    int mperm = 2 * nl + (y & 1);   // k'-interleave matching kAttn's P order
#pragma unroll
    for (int r = 0; r < 4; ++r) {
      float val = acc[st][r];
      int oo = (oq & 1) * 16 + quad * 4 + r;   // index within 32-ch group
      if (oq < 2) {
        out[(size_t)(b * 64 + oo) * 4096 + s] = val;
      } else if (oq < 4) {
        int h = oo >> 3, c = oo & 7;
        Qbf[((size_t)(b * 4 + h) * 4096 + s) * 8 + c] = f2bf(val);
      } else if (oq < 6) {
        int h = oo >> 3, c = oo & 7;
        Kbf[((size_t)(b * 4 + h) * 4096 + s) * 8 + c] = f2bf(val);
      } else {
        int h = oo >> 3, c = oo & 7;
        VtTp[((size_t)((b * 4 + h) * 16) + c) * 4096 + (size_t)(s & ~31) + mperm] = f2bf(val);
      }
    }
  }
}

// MFMA attention, key-split KSP, 2 n-tiles (32 query rows) per wave.
// Grid = 256*KSP blocks x 4 waves. Each wave: 32 rows x (4096/KSP) keys.
// K loaded FULL-WAVE (lane -> row m0+(lane&31)); two Q A-variants (k-octet
// 0 / 1) extract keys 0..15 / 16..31 from one load. P LDS round-trip
// read-BEFORE-write pipelined. PV B-operand: plain full-wave load from the
// 16-row VtTp (rows 0-7 V, row 8 ones -> row-sum l, rows 9-15 zero) —
// no per-chunk cndmask select.
template <int KSP>
__global__ __launch_bounds__(256) void kAttn(const ushort_t* __restrict__ Qbf,
                                             const ushort_t* __restrict__ Kbf,
                                             const ushort_t* __restrict__ VtTp,
                                             float* __restrict__ pacc,
                                             float* __restrict__ pl) {
  const int NCH = 128 / KSP;                  // 32-key chunks per wave
  __shared__ ushort_t Plds[4 * 2 * 2 * 640];  // [wave][tile][buf][16*40]
  int tid = threadIdx.x;
  int w = tid >> 6, lane = tid & 63;
  int id = blockIdx.x * 4 + w;               // [0, 1024*KSP)
  int bh = id / (KSP * 128);                 // [0,8)
  int rem = id % (KSP * 128);
  int ksp = rem >> 7;                        // key split [0,KSP)
  int ntile = rem & 127;                     // [0,128)
  int n0 = ntile * 32;
  int quad = lane >> 4, nl = lane & 15;
  int l31 = lane & 31;
  int v = nl;                                // [0,16): VtTp row (8=ones, >8=0)

  short8 z8 = {};
  short8 q0f = *(const short8*)(Qbf + ((size_t)bh * 4096 + n0 + nl) * 8);
  short8 q1f = *(const short8*)(Qbf + ((size_t)bh * 4096 + n0 + 16 + nl) * 8);
  short8 aq0A = (quad == 0) ? q0f : z8;   // tile0, Q in k-octet 0 -> keys 0..15
  short8 aq0B = (quad == 1) ? q0f : z8;   // tile0, Q in k-octet 1 -> keys 16..31
  short8 aq1A = (quad == 0) ? q1f : z8;
  short8 aq1B = (quad == 1) ? q1f : z8;

  const ushort_t* Krows = Kbf + ((size_t)bh * 4096 + ksp * (4096 / KSP)) * 8;
  const ushort_t* Vrow = VtTp + ((size_t)(bh * 16 + v)) * 4096
                         + ksp * (4096 / KSP) + quad * 8;
  ushort_t* P0 = Plds + (w * 2 + 0) * 2 * 640;
  ushort_t* P1 = Plds + (w * 2 + 1) * 2 * 640;

  float4v acc0 = {}, acc1 = {};

#define QKEXP(mi, bkr)                                                         \
  {                                                                            \
    float4v s00 = __builtin_amdgcn_mfma_f32_16x16x32_bf16(                     \
        aq0A, bkr, (float4v){0.f, 0.f, 0.f, 0.f}, 0, 0, 0);                    \
    float4v s01 = __builtin_amdgcn_mfma_f32_16x16x32_bf16(                     \
        aq0B, bkr, (float4v){0.f, 0.f, 0.f, 0.f}, 0, 0, 0);                    \
    float4v s10 = __builtin_amdgcn_mfma_f32_16x16x32_bf16(                     \
        aq1A, bkr, (float4v){0.f, 0.f, 0.f, 0.f}, 0, 0, 0);                    \
    float4v s11 = __builtin_amdgcn_mfma_f32_16x16x32_bf16(                     \
        aq1B, bkr, (float4v){0.f, 0.f, 0.f, 0.f}, 0, 0, 0);                    \
    uint_t* Pt0 = (uint_t*)(P0 + ((mi) & 1) * 640);                            \
    uint_t* Pt1 = (uint_t*)(P1 + ((mi) & 1) * 640);                            \
    _Pragma("unroll") for (int r = 0; r < 4; ++r) {                            \
      Pt0[(quad * 4 + r) * 20 + nl] =                                          \
          cvtpk(__builtin_amdgcn_exp2f(s00[r]), __builtin_amdgcn_exp2f(s01[r]));\
      Pt1[(quad * 4 + r) * 20 + nl] =                                          \
          cvtpk(__builtin_amdgcn_exp2f(s10[r]), __builtin_amdgcn_exp2f(s11[r]));\
    }                                                                          \
  }

  short8 bk = *(const short8*)(Krows + (size_t)l31 * 8);       // chunk 0
  QKEXP(0, bk)
  bk = *(const short8*)(Krows + (size_t)(32 + l31) * 8);       // chunk 1

#pragma unroll 2
  for (int mi = 1; mi < NCH; ++mi) {
    int pb = ((mi - 1) & 1) * 640;
    // read P(mi-1) FIRST: its latency hides under this chunk's QK/exp/writes
    short8 a20 = *(const short8*)(P0 + pb + nl * 40 + quad * 8);
    short8 a21 = *(const short8*)(P1 + pb + nl * 40 + quad * 8);
    short8 bv = *(const short8*)(Vrow + (mi - 1) * 32);
    QKEXP(mi, bk)
    int nxt = ((mi + 1) & (NCH - 1)) * 32;                     // wrap (dummy last)
    bk = *(const short8*)(Krows + (size_t)(nxt + l31) * 8);
    acc0 = __builtin_amdgcn_mfma_f32_16x16x32_bf16(a20, bv, acc0, 0, 0, 0);
    acc1 = __builtin_amdgcn_mfma_f32_16x16x32_bf16(a21, bv, acc1, 0, 0, 0);
  }
  {
    int pb = ((NCH - 1) & 1) * 640;
    short8 a20 = *(const short8*)(P0 + pb + nl * 40 + quad * 8);
    short8 a21 = *(const short8*)(P1 + pb + nl * 40 + quad * 8);
    short8 bv = *(const short8*)(Vrow + (NCH - 1) * 32);
    acc0 = __builtin_amdgcn_mfma_f32_16x16x32_bf16(a20, bv, acc0, 0, 0, 0);
    acc1 = __builtin_amdgcn_mfma_f32_16x16x32_bf16(a21, bv, acc1, 0, 0, 0);
  }
#undef QKEXP

  // acc: O-partial[n][v] at col=v=nl, row=quad*4+r; col 8 = partial row-sum l.
#pragma unroll
  for (int r = 0; r < 4; ++r) {
    int rq = quad * 4 + r;
    int rowg0 = bh * 4096 + n0 + rq;           // [0, 32768)
    int rowg1 = rowg0 + 16;
    if (v < 8) {
      pacc[((size_t)rowg0 * KSP + ksp) * 8 + v] = acc0[r];
      pacc[((size_t)rowg1 * KSP + ksp) * 8 + v] = acc1[r];
    } else if (v == 8) {
      pl[(size_t)rowg0 * KSP + ksp] = acc0[r];
      pl[(size_t)rowg1 * KSP + ksp] = acc1[r];
    }
  }
}

// Fused merge + 1x1x1 conv + bias -> out channels 32..63.
// Block = (b, 64-spatial tile); grid 128. Phase 1: merge the KSP key-split
// partials into LDS M[ci(32)][spl(64)] applying the reference's faithful
// reshape (attnR[ci][sp]: h=ci>>3, n=(ci&7)*512+(sp>>3), c=sp&7).
// Phase 2: 32->32 channel conv from LDS, coalesced stores.
template <int KSP>
__global__ __launch_bounds__(256) void kOut(const float* __restrict__ pacc,
                                            const float* __restrict__ pl,
                                            const float* __restrict__ w_out,
                                            const float* __restrict__ b_out,
                                            float* __restrict__ out) {
  __shared__ float M[32 * 64];   // 8 KB
  int bx = blockIdx.x;           // [0,128) = b*64 + spt
  int b = bx >> 6;
  int sp0 = (bx & 63) * 64;
  int t = threadIdx.x;

  // phase 1: thread t -> ci = t>>3, nsub = t&7
  {
    int ci = t >> 3, nsub = t & 7;
    int h = ci >> 3, tt = ci & 7;
    int n = tt * 512 + (sp0 >> 3) + nsub;
    size_t row = (size_t)(b * 4 + h) * 4096 + n;
    float l = 0.f;
#pragma unroll
    for (int s = 0; s < KSP; ++s) l += pl[row * KSP + s];
    float rl = 1.0f / l;
    float m[8];
#pragma unroll
    for (int c = 0; c < 8; ++c) m[c] = 0.f;
#pragma unroll
    for (int s = 0; s < KSP; ++s) {
      const float4 p0 = *(const float4*)(pacc + (row * KSP + s) * 8);
      const float4 p1 = *(const float4*)(pacc + (row * KSP + s) * 8 + 4);
      m[0] += p0.x; m[1] += p0.y; m[2] += p0.z; m[3] += p0.w;
      m[4] += p1.x; m[5] += p1.y; m[6] += p1.z; m[7] += p1.w;
    }
    float4 o0 = {m[0] * rl, m[1] * rl, m[2] * rl, m[3] * rl};
    float4 o1 = {m[4] * rl, m[5] * rl, m[6] * rl, m[7] * rl};
    *(float4*)(M + ci * 64 + nsub * 8) = o0;
    *(float4*)(M + ci * 64 + nsub * 8 + 4) = o1;
  }
  __syncthreads();

  // phase 2: thread t -> spl = t&63, co-group t>>6 (8 channels each)
  {
    int spl = t & 63;
    int cog = t >> 6;              // wave-uniform
    float a[32];
#pragma unroll
    for (int ci = 0; ci < 32; ++ci) a[ci] = M[ci * 64 + spl];
#pragma unroll
    for (int oo = 0; oo < 8; ++oo) {
      int co = cog * 8 + oo;
      float r = b_out[co];
#pragma unroll
      for (int ci = 0; ci < 32; ++ci) r = fmaf(w_out[co * 32 + ci], a[ci], r);
      out[(size_t)(b * 64 + 32 + co) * 4096 + sp0 + spl] = r;
    }
  }
}

extern "C" void kernel_launch(void* const* d_in, const int* in_sizes, int n_in,
                              void* d_out, int out_size, void* d_ws, size_t ws_size,
                              hipStream_t stream) {
  const float* x      = (const float*)d_in[0];
  const float* w_init = (const float*)d_in[1];
  const float* w_qkv  = (const float*)d_in[2];
  const float* w_out  = (const float*)d_in[3];
  const float* b_out  = (const float*)d_in[4];
  float* out = (float*)d_out;

  // ws layout (bytes): Qbf 524288 | Kbf 524288 | VtTp 1048576 (16 v-rows) |
  //   pacc KSP*1048576 | pl KSP*131072. KSP=8 needs 11.5 MB (ws_size is
  //   256 MiB measured; guard kept as insurance for smaller ws).
  const size_t fixed = 2 * 524288 + 1048576;
  int KSP = (ws_size >= fixed + (size_t)8 * (1048576 + 131072)) ? 8 : 4;

  ushort_t* Qbf = (ushort_t*)d_ws;
  ushort_t* Kbf = Qbf + 262144;
  ushort_t* VtTp = Kbf + 262144;            // 524288 u16 (16 rows per bh)
  float* pacc = (float*)(VtTp + 524288);
  float* pl = pacc + (size_t)KSP * 262144;

  kConv <<<256, 256, 0, stream>>>(x, w_init, w_qkv, out, Qbf, Kbf, VtTp);
  if (KSP == 8) {
    kAttn<8><<<2048, 256, 0, stream>>>(Qbf, Kbf, VtTp, pacc, pl);
    kOut<8> <<<128, 256, 0, stream>>>(pacc, pl, w_out, b_out, out);
  } else {
    kAttn<4><<<1024, 256, 0, stream>>>(Qbf, Kbf, VtTp, pacc, pl);
    kOut<4> <<<128, 256, 0, stream>>>(pacc, pl, w_out, b_out, out);
  }
}

// Round 15
// 102.304 us; speedup vs baseline: 1.0462x; 1.0462x over previous
//
#include <hip/hip_runtime.h>

// ---------------------------------------------------------------------------
// x(2,32,16,16,16), w_init(32,32,27), w_qkv(96,32,27), w_out(32,32), b_out(32).
// out(2,64,4096). heads=4, dk_h=dv_h=8, N=4096, scale=8^-0.5 (folded into the
// q-weights together with log2e; softmax uses exp2).
// 3 kernels: kConv (self-staging: weights + x transpose fused in-block;
// 27 tap-shifted bf16 MFMA GEMMs, K=32=ic, kz-plane-wise), kAttn (bf16 MFMA,
// key-split KSP, 2 n-tiles/wave, full-wave K loads + dual Q A-variants,
// read-before-write P pipeline), kOut (merge + 1x1x1 conv fused).
// VERIFIED BASELINE (102.5 us, absmax 0.073): r13 (branchless 16-row VtTp)
// regressed to 107; r14 (S^T QK, b64 P-writes) failed correctness 0.1246 —
// sparse-octet trick on the B operand is NOT verified; keep it on A only.
// ---------------------------------------------------------------------------

typedef short short8 __attribute__((ext_vector_type(8)));
typedef float float4v __attribute__((ext_vector_type(4)));
typedef unsigned short ushort_t;
typedef unsigned int uint_t;

__device__ inline ushort_t f2bf(float x) {   // fp32 -> bf16 RNE (scalar path)
  uint_t u = __builtin_bit_cast(uint_t, x);
  u += 0x7FFFu + ((u >> 16) & 1u);
  return (ushort_t)(u >> 16);
}

__device__ inline uint_t cvtpk(float lo, float hi) {  // packed bf16x2, RNE, 1 inst
  uint_t r;
  asm("v_cvt_pk_bf16_f32 %0, %1, %2" : "=v"(r) : "v"(lo), "v"(hi));
  return r;
}

// MFMA conv, fully self-staging. Block=(b,z,oq), grid 256 (1 block/CU), 4 waves.
// Phase W: stage this block's CONTIGUOUS 54KB weight slice (o-major layout!)
//   into wl[tap(27)][lane(64)][j(8)] bf16: o = oq*16 + (lane&15),
//   ic = (lane>>4)*8 + j. q-tiles (oq 2,3) pre-scaled by QS.
// Phase X (per kz): transpose wrapped z-plane x fp32 (b,ic,s) -> xs[s][ic]
//   bf16 via 34-padded LDS staging (2 halves of 128 rows), then 9 taps of
//   MFMA: afrag = ds_read_b128 from wl, bfrag = ds_read_b128 from xs.
// LDS: 16KB xs + 17.4KB xsf + 27KB wl = 60.4KB (static, under 64KB).
__global__ __launch_bounds__(256, 1) void kConv(const float* __restrict__ x,
                                                const float* __restrict__ w_init,
                                                const float* __restrict__ w_qkv,
                                                float* __restrict__ out,
                                                ushort_t* __restrict__ Qbf,
                                                ushort_t* __restrict__ Kbf,
                                                ushort_t* __restrict__ VtTp) {
  __shared__ ushort_t wl[27 * 512];     // 27 KB
  __shared__ ushort_t xs[256 * 32];     // 16 KB: one z-plane, [s=y*16+x][ic]
  __shared__ float xsf[128 * 34];       // 17 KB: half-plane transpose staging
  int tid = threadIdx.x;
  int w = tid >> 6, lane = tid & 63;
  int quad = lane >> 4, nl = lane & 15;
  int bx = blockIdx.x;              // [0,256) = b*128 + z*8 + oq
  int oq = bx & 7;
  int z = (bx >> 3) & 15;
  int b = bx >> 7;

  // ---- Phase W: weight slice -> wl (contiguous 3456 float4 reads)
  const float* wsrc = (oq < 2) ? (w_init + (size_t)oq * 16 * 864)
                               : (w_qkv + (size_t)(oq - 2) * 16 * 864);  // 864=32*27
  const float QS = 0.35355339059327373f * 1.4426950408889634f;
  float wscale = (oq == 2 || oq == 3) ? QS : 1.0f;
#pragma unroll
  for (int i = 0; i < 14; ++i) {
    int idx4 = i * 256 + tid;          // float4 index [0, 3456)
    if (idx4 < 3456) {
      float4 v = *(const float4*)(wsrc + (size_t)idx4 * 4);
      float vv[4] = {v.x, v.y, v.z, v.w};
#pragma unroll
      for (int k = 0; k < 4; ++k) {
        int e = idx4 * 4 + k;          // = (oo*32 + ic)*27 + tap
        int tap = e % 27;
        int rest = e / 27;
        int ic = rest & 31;
        int oo = rest >> 5;
        wl[tap * 512 + ((ic >> 3) * 16 + oo) * 8 + (ic & 7)] = f2bf(vv[k] * wscale);
      }
    }
  }

  float4v acc[4];
#pragma unroll
  for (int st = 0; st < 4; ++st) acc[st] = (float4v){0.f, 0.f, 0.f, 0.f};
  int y0 = w * 4;

  for (int kz = 0; kz < 3; ++kz) {
    int zr = (z + kz + 15) & 15;
    // ---- Phase X: stage plane zr -> xs[s][ic] bf16, in 2 halves of 128 rows
#pragma unroll
    for (int h = 0; h < 2; ++h) {
      __syncthreads();   // xsf free (prev pack / prev kz's mfma reads done)
      int rloc = tid & 127;
      int ich = tid >> 7;              // 0..1 -> ic 0..15 / 16..31
#pragma unroll
      for (int icq = 0; icq < 16; ++icq) {
        int ic = ich * 16 + icq;
        xsf[rloc * 34 + ic] = x[((size_t)(b * 32 + ic) * 16 + zr) * 256 + h * 128 + rloc];
      }
      __syncthreads();
#pragma unroll
      for (int r = 0; r < 2; ++r) {
        int slot = r * 256 + tid;      // [0,512) = 128 rows x 4 ic-groups
        int sl = slot >> 2;
        int icg = slot & 3;
        ushort_t tmp[8];
#pragma unroll
        for (int jj = 0; jj < 8; ++jj) tmp[jj] = f2bf(xsf[sl * 34 + icg * 8 + jj]);
        *(short8*)(xs + (h * 128 + sl) * 32 + icg * 8) = *(short8*)tmp;
      }
    }
    __syncthreads();

    // ---- 9 taps of this kz-plane
#pragma unroll
    for (int kyx = 0; kyx < 9; ++kyx) {
      int ky = kyx / 3, kx = kyx % 3;
      int tap = kz * 9 + kyx;
      short8 afrag = *(const short8*)(wl + tap * 512 + lane * 8);
      int xsh = (nl + kx + 15) & 15;
#pragma unroll
      for (int st = 0; st < 4; ++st) {
        int yy = (y0 + st + ky + 15) & 15;
        short8 bfrag = *(const short8*)(xs + (yy * 16 + xsh) * 32 + quad * 8);
        acc[st] = __builtin_amdgcn_mfma_f32_16x16x32_bf16(afrag, bfrag, acc[st], 0, 0, 0);
      }
    }
  }

  // Epilogue. C layout: col = nl (spatial x), row = quad*4 + r (o in tile).
#pragma unroll
  for (int st = 0; st < 4; ++st) {
    int y = y0 + st;
    int s = z * 256 + y * 16 + nl;
    int mperm = 2 * nl + (y & 1);   // k'-interleave matching kAttn's P order
#pragma unroll
    for (int r = 0; r < 4; ++r) {
      float val = acc[st][r];
      int oo = (oq & 1) * 16 + quad * 4 + r;   // index within 32-ch group
      if (oq < 2) {
        out[(size_t)(b * 64 + oo) * 4096 + s] = val;
      } else if (oq < 4) {
        int h = oo >> 3, c = oo & 7;
        Qbf[((size_t)(b * 4 + h) * 4096 + s) * 8 + c] = f2bf(val);
      } else if (oq < 6) {
        int h = oo >> 3, c = oo & 7;
        Kbf[((size_t)(b * 4 + h) * 4096 + s) * 8 + c] = f2bf(val);
      } else {
        int h = oo >> 3, c = oo & 7;
        VtTp[((size_t)(b * 4 + h) * 8 + c) * 4096 + (size_t)(s & ~31) + mperm] = f2bf(val);
      }
    }
  }
}

// MFMA attention, key-split KSP, 2 n-tiles (32 query rows) per wave.
// Grid = 256*KSP blocks x 4 waves. Each wave: 32 rows x (4096/KSP) keys.
// K loaded FULL-WAVE (lane -> row m0+(lane&31)); two Q A-variants (k-octet
// 0 / 1) extract keys 0..15 / 16..31 from one load. P LDS round-trip
// read-BEFORE-write pipelined. PV B-operand: V ch 0..7, ones at v=8
// (row-sum l for free), zeros above.
template <int KSP>
__global__ __launch_bounds__(256) void kAttn(const ushort_t* __restrict__ Qbf,
                                             const ushort_t* __restrict__ Kbf,
                                             const ushort_t* __restrict__ VtTp,
                                             float* __restrict__ pacc,
                                             float* __restrict__ pl) {
  const int NCH = 128 / KSP;                  // 32-key chunks per wave
  __shared__ ushort_t Plds[4 * 2 * 2 * 640];  // [wave][tile][buf][16*40]
  int tid = threadIdx.x;
  int w = tid >> 6, lane = tid & 63;
  int id = blockIdx.x * 4 + w;               // [0, 1024*KSP)
  int bh = id / (KSP * 128);                 // [0,8)
  int rem = id % (KSP * 128);
  int ksp = rem >> 7;                        // key split [0,KSP)
  int ntile = rem & 127;                     // [0,128)
  int n0 = ntile * 32;
  int quad = lane >> 4, nl = lane & 15;
  int l31 = lane & 31;
  int v = nl;

  short8 z8 = {};
  short8 q0f = *(const short8*)(Qbf + ((size_t)bh * 4096 + n0 + nl) * 8);
  short8 q1f = *(const short8*)(Qbf + ((size_t)bh * 4096 + n0 + 16 + nl) * 8);
  short8 aq0A = (quad == 0) ? q0f : z8;   // tile0, Q in k-octet 0 -> keys 0..15
  short8 aq0B = (quad == 1) ? q0f : z8;   // tile0, Q in k-octet 1 -> keys 16..31
  short8 aq1A = (quad == 0) ? q1f : z8;
  short8 aq1B = (quad == 1) ? q1f : z8;

  short8 ones8;
#pragma unroll
  for (int i = 0; i < 8; ++i) ones8[i] = (short)0x3F80;  // bf16 1.0

  const ushort_t* Krows = Kbf + ((size_t)bh * 4096 + ksp * (4096 / KSP)) * 8;
  const ushort_t* Vrow = VtTp + ((size_t)(bh * 8 + (v < 8 ? v : 0))) * 4096
                         + ksp * (4096 / KSP) + quad * 8;
  ushort_t* P0 = Plds + (w * 2 + 0) * 2 * 640;
  ushort_t* P1 = Plds + (w * 2 + 1) * 2 * 640;

  float4v acc0 = {}, acc1 = {};

#define QKEXP(mi, bkr)                                                         \
  {                                                                            \
    float4v s00 = __builtin_amdgcn_mfma_f32_16x16x32_bf16(                     \
        aq0A, bkr, (float4v){0.f, 0.f, 0.f, 0.f}, 0, 0, 0);                    \
    float4v s01 = __builtin_amdgcn_mfma_f32_16x16x32_bf16(                     \
        aq0B, bkr, (float4v){0.f, 0.f, 0.f, 0.f}, 0, 0, 0);                    \
    float4v s10 = __builtin_amdgcn_mfma_f32_16x16x32_bf16(                     \
        aq1A, bkr, (float4v){0.f, 0.f, 0.f, 0.f}, 0, 0, 0);                    \
    float4v s11 = __builtin_amdgcn_mfma_f32_16x16x32_bf16(                     \
        aq1B, bkr, (float4v){0.f, 0.f, 0.f, 0.f}, 0, 0, 0);                    \
    uint_t* Pt0 = (uint_t*)(P0 + ((mi) & 1) * 640);                            \
    uint_t* Pt1 = (uint_t*)(P1 + ((mi) & 1) * 640);                            \
    _Pragma("unroll") for (int r = 0; r < 4; ++r) {                            \
      Pt0[(quad * 4 + r) * 20 + nl] =                                          \
          cvtpk(__builtin_amdgcn_exp2f(s00[r]), __builtin_amdgcn_exp2f(s01[r]));\
      Pt1[(quad * 4 + r) * 20 + nl] =                                          \
          cvtpk(__builtin_amdgcn_exp2f(s10[r]), __builtin_amdgcn_exp2f(s11[r]));\
    }                                                                          \
  }

#define PVSTEP(a2, bv, accv)                                                   \
  {                                                                            \
    short8 b2 = (v < 8) ? (bv) : ((v == 8) ? ones8 : z8);                      \
    accv = __builtin_amdgcn_mfma_f32_16x16x32_bf16(a2, b2, accv, 0, 0, 0);     \
  }

  short8 bk = *(const short8*)(Krows + (size_t)l31 * 8);       // chunk 0
  QKEXP(0, bk)
  bk = *(const short8*)(Krows + (size_t)(32 + l31) * 8);       // chunk 1

#pragma unroll 2
  for (int mi = 1; mi < NCH; ++mi) {
    int pb = ((mi - 1) & 1) * 640;
    // read P(mi-1) FIRST: its latency hides under this chunk's QK/exp/writes
    short8 a20 = *(const short8*)(P0 + pb + nl * 40 + quad * 8);
    short8 a21 = *(const short8*)(P1 + pb + nl * 40 + quad * 8);
    short8 bv = *(const short8*)(Vrow + (mi - 1) * 32);
    QKEXP(mi, bk)
    int nxt = ((mi + 1) & (NCH - 1)) * 32;                     // wrap (dummy last)
    bk = *(const short8*)(Krows + (size_t)(nxt + l31) * 8);
    PVSTEP(a20, bv, acc0)
    PVSTEP(a21, bv, acc1)
  }
  {
    int pb = ((NCH - 1) & 1) * 640;
    short8 a20 = *(const short8*)(P0 + pb + nl * 40 + quad * 8);
    short8 a21 = *(const short8*)(P1 + pb + nl * 40 + quad * 8);
    short8 bv = *(const short8*)(Vrow + (NCH - 1) * 32);
    PVSTEP(a20, bv, acc0)
    PVSTEP(a21, bv, acc1)
  }
#undef QKEXP
#undef PVSTEP

  // acc: O-partial[n][v] at col=v=nl, row=quad*4+r; col 8 = partial row-sum l.
#pragma unroll
  for (int r = 0; r < 4; ++r) {
    int rq = quad * 4 + r;
    int rowg0 = bh * 4096 + n0 + rq;           // [0, 32768)
    int rowg1 = rowg0 + 16;
    if (v < 8) {
      pacc[((size_t)rowg0 * KSP + ksp) * 8 + v] = acc0[r];
      pacc[((size_t)rowg1 * KSP + ksp) * 8 + v] = acc1[r];
    } else if (v == 8) {
      pl[(size_t)rowg0 * KSP + ksp] = acc0[r];
      pl[(size_t)rowg1 * KSP + ksp] = acc1[r];
    }
  }
}

// Fused merge + 1x1x1 conv + bias -> out channels 32..63.
// Block = (b, 64-spatial tile); grid 128. Phase 1: merge the KSP key-split
// partials into LDS M[ci(32)][spl(64)] applying the reference's faithful
// reshape (attnR[ci][sp]: h=ci>>3, n=(ci&7)*512+(sp>>3), c=sp&7).
// Phase 2: 32->32 channel conv from LDS, coalesced stores.
template <int KSP>
__global__ __launch_bounds__(256) void kOut(const float* __restrict__ pacc,
                                            const float* __restrict__ pl,
                                            const float* __restrict__ w_out,
                                            const float* __restrict__ b_out,
                                            float* __restrict__ out) {
  __shared__ float M[32 * 64];   // 8 KB
  int bx = blockIdx.x;           // [0,128) = b*64 + spt
  int b = bx >> 6;
  int sp0 = (bx & 63) * 64;
  int t = threadIdx.x;

  // phase 1: thread t -> ci = t>>3, nsub = t&7
  {
    int ci = t >> 3, nsub = t & 7;
    int h = ci >> 3, tt = ci & 7;
    int n = tt * 512 + (sp0 >> 3) + nsub;
    size_t row = (size_t)(b * 4 + h) * 4096 + n;
    float l = 0.f;
#pragma unroll
    for (int s = 0; s < KSP; ++s) l += pl[row * KSP + s];
    float rl = 1.0f / l;
    float m[8];
#pragma unroll
    for (int c = 0; c < 8; ++c) m[c] = 0.f;
#pragma unroll
    for (int s = 0; s < KSP; ++s) {
      const float4 p0 = *(const float4*)(pacc + (row * KSP + s) * 8);
      const float4 p1 = *(const float4*)(pacc + (row * KSP + s) * 8 + 4);
      m[0] += p0.x; m[1] += p0.y; m[2] += p0.z; m[3] += p0.w;
      m[4] += p1.x; m[5] += p1.y; m[6] += p1.z; m[7] += p1.w;
    }
    float4 o0 = {m[0] * rl, m[1] * rl, m[2] * rl, m[3] * rl};
    float4 o1 = {m[4] * rl, m[5] * rl, m[6] * rl, m[7] * rl};
    *(float4*)(M + ci * 64 + nsub * 8) = o0;
    *(float4*)(M + ci * 64 + nsub * 8 + 4) = o1;
  }
  __syncthreads();

  // phase 2: thread t -> spl = t&63, co-group t>>6 (8 channels each)
  {
    int spl = t & 63;
    int cog = t >> 6;              // wave-uniform
    float a[32];
#pragma unroll
    for (int ci = 0; ci < 32; ++ci) a[ci] = M[ci * 64 + spl];
#pragma unroll
    for (int oo = 0; oo < 8; ++oo) {
      int co = cog * 8 + oo;
      float r = b_out[co];
#pragma unroll
      for (int ci = 0; ci < 32; ++ci) r = fmaf(w_out[co * 32 + ci], a[ci], r);
      out[(size_t)(b * 64 + 32 + co) * 4096 + sp0 + spl] = r;
    }
  }
}

extern "C" void kernel_launch(void* const* d_in, const int* in_sizes, int n_in,
                              void* d_out, int out_size, void* d_ws, size_t ws_size,
                              hipStream_t stream) {
  const float* x      = (const float*)d_in[0];
  const float* w_init = (const float*)d_in[1];
  const float* w_qkv  = (const float*)d_in[2];
  const float* w_out  = (const float*)d_in[3];
  const float* b_out  = (const float*)d_in[4];
  float* out = (float*)d_out;

  // ws layout (bytes): Qbf 524288 | Kbf 524288 | VtTp 524288 |
  //   pacc KSP*1048576 | pl KSP*131072. KSP=8 needs 11.0 MB (ws_size is
  //   256 MiB measured; guard kept as insurance for smaller ws).
  const size_t fixed = 3 * 524288;
  int KSP = (ws_size >= fixed + (size_t)8 * (1048576 + 131072)) ? 8 : 4;

  ushort_t* Qbf = (ushort_t*)d_ws;
  ushort_t* Kbf = Qbf + 262144;
  ushort_t* VtTp = Kbf + 262144;
  float* pacc = (float*)(VtTp + 262144);
  float* pl = pacc + (size_t)KSP * 262144;

  kConv <<<256, 256, 0, stream>>>(x, w_init, w_qkv, out, Qbf, Kbf, VtTp);
  if (KSP == 8) {
    kAttn<8><<<2048, 256, 0, stream>>>(Qbf, Kbf, VtTp, pacc, pl);
    kOut<8> <<<128, 256, 0, stream>>>(pacc, pl, w_out, b_out, out);
  } else {
    kAttn<4><<<1024, 256, 0, stream>>>(Qbf, Kbf, VtTp, pacc, pl);
    kOut<4> <<<128, 256, 0, stream>>>(pacc, pl, w_out, b_out, out);
  }
}